// Round 3
// baseline (2502.493 us; speedup 1.0000x reference)
//
#include <hip/hip_runtime.h>
#include <hip/hip_fp16.h>
#include <math.h>
#include <string.h>

#define N_ROWS 2000000
#define C 20
#define K 9
#define EPS 1e-5f

#define GRID_RED 2048
#define BLK 256

typedef float f32x4 __attribute__((ext_vector_type(4)));
typedef unsigned int u32x4 __attribute__((ext_vector_type(4)));
typedef unsigned int u32x2 __attribute__((ext_vector_type(2)));

template <typename T> __device__ inline T ntl(const T* p) { return __builtin_nontemporal_load(p); }
template <typename T> __device__ inline void nts(T* p, T v) { __builtin_nontemporal_store(v, p); }

// ---------- fp16 pack/unpack (2 elems per uint) ----------

__device__ inline unsigned int pk2(float a, float b) {
    __half2 h = __floats2half2_rn(a, b);
    unsigned int u;
    memcpy(&u, &h, 4);
    return u;
}

__device__ inline void upk2(unsigned int u, float& a, float& b) {
    __half2 h;
    memcpy(&h, &u, 4);
    float2 f = __half22float2(h);
    a = f.x;
    b = f.y;
}

// RPU = uints per row (16 -> 64B padded rows, 10 -> 40B packed rows)
template <int RPU>
__device__ inline void load_row_h(const unsigned int* __restrict__ p, float* v) {
    unsigned int u[10];
    if constexpr (RPU == 16) {
        u32x4 a = *(const u32x4*)p;
        u32x4 b = *(const u32x4*)(p + 4);
        u32x2 c = *(const u32x2*)(p + 8);
        u[0] = a.x; u[1] = a.y; u[2] = a.z; u[3] = a.w;
        u[4] = b.x; u[5] = b.y; u[6] = b.z; u[7] = b.w;
        u[8] = c.x; u[9] = c.y;
    } else {
#pragma unroll
        for (int i = 0; i < 5; i++) {
            u32x2 t = *(const u32x2*)(p + 2 * i);
            u[2 * i] = t.x;
            u[2 * i + 1] = t.y;
        }
    }
#pragma unroll
    for (int i = 0; i < 10; i++) upk2(u[i], v[2 * i], v[2 * i + 1]);
}

template <int RPU>
__device__ inline void store_row_h(unsigned int* __restrict__ p, const float* v) {
    unsigned int u[10];
#pragma unroll
    for (int i = 0; i < 10; i++) u[i] = pk2(v[2 * i], v[2 * i + 1]);
    if constexpr (RPU == 16) {
        u32x4 a; a.x = u[0]; a.y = u[1]; a.z = u[2]; a.w = u[3];
        u32x4 b; b.x = u[4]; b.y = u[5]; b.z = u[6]; b.w = u[7];
        u32x2 c; c.x = u[8]; c.y = u[9];
        *(u32x4*)p = a;
        *(u32x4*)(p + 4) = b;
        *(u32x2*)(p + 8) = c;
    } else {
#pragma unroll
        for (int i = 0; i < 5; i++) {
            u32x2 t; t.x = u[2 * i]; t.y = u[2 * i + 1];
            *(u32x2*)(p + 2 * i) = t;
        }
    }
}

// ---------- fp32 row helpers ----------

__device__ inline void load_row20_nt(const float* __restrict__ p, float* v) {
    const f32x4* q = (const f32x4*)p;
#pragma unroll
    for (int i = 0; i < 5; i++) {
        f32x4 t = ntl(q + i);
        v[4 * i + 0] = t.x; v[4 * i + 1] = t.y; v[4 * i + 2] = t.z; v[4 * i + 3] = t.w;
    }
}

__device__ inline void store_row20_nt(float* __restrict__ p, const float* v) {
    f32x4* q = (f32x4*)p;
#pragma unroll
    for (int i = 0; i < 5; i++) {
        f32x4 t;
        t.x = v[4 * i + 0]; t.y = v[4 * i + 1]; t.z = v[4 * i + 2]; t.w = v[4 * i + 3];
        nts(q + i, t);
    }
}

// ---------- reductions ----------

__device__ inline float wave_sum(float v) {
    v += __shfl_xor(v, 1);
    v += __shfl_xor(v, 2);
    v += __shfl_xor(v, 4);
    v += __shfl_xor(v, 8);
    v += __shfl_xor(v, 16);
    v += __shfl_xor(v, 32);
    return v;
}

__device__ inline void block_reduce_partials(float* vals, float* __restrict__ partials) {
    __shared__ float sred[BLK / 64][2 * C];
    const int lane = threadIdx.x & 63;
    const int wid = threadIdx.x >> 6;
#pragma unroll
    for (int i = 0; i < 2 * C; i++) vals[i] = wave_sum(vals[i]);
    if (lane == 0) {
#pragma unroll
        for (int i = 0; i < 2 * C; i++) sred[wid][i] = vals[i];
    }
    __syncthreads();
    if (threadIdx.x < 2 * C) {
        float s = 0.f;
#pragma unroll
        for (int w = 0; w < BLK / 64; w++) s += sred[w][threadIdx.x];
        partials[(size_t)blockIdx.x * (2 * C) + threadIdx.x] = s;
    }
}

// ---------- kA: BN1 stats of feature@W1+b1 (no y1 materialization) ----------

__global__ __launch_bounds__(BLK, 3) void kA(const float* __restrict__ feat,
                                             const float* __restrict__ W1,
                                             const float* __restrict__ b1,
                                             float* __restrict__ partials) {
    float sums[2 * C];
#pragma unroll
    for (int i = 0; i < 2 * C; i++) sums[i] = 0.f;

    for (int r = blockIdx.x * BLK + threadIdx.x; r < N_ROWS; r += GRID_RED * BLK) {
        float f[C];
        load_row20_nt(feat + (size_t)r * C, f);
        float y[C];
#pragma unroll
        for (int c = 0; c < C; c++) y[c] = b1[c];
#pragma unroll
        for (int i = 0; i < C; i++) {
            float fi = f[i];
#pragma unroll
            for (int c = 0; c < C; c++) y[c] = fmaf(fi, W1[i * C + c], y[c]);
        }
#pragma unroll
        for (int c = 0; c < C; c++) {
            sums[c] += y[c];
            sums[C + c] = fmaf(y[c], y[c], sums[C + c]);
        }
    }
    block_reduce_partials(sums, partials);
}

// ---------- kFin: partials -> scale/shift ----------

__global__ __launch_bounds__(640) void kFin(const float* __restrict__ partials,
                                            const float* __restrict__ g,
                                            const float* __restrict__ be,
                                            float* __restrict__ ss) {
    const int c = threadIdx.x >> 4;
    const int r = threadIdx.x & 15;
    __shared__ float tot[2 * C];
    {
        float s = 0.f;
        for (int b = r; b < GRID_RED; b += 16) s += partials[(size_t)b * (2 * C) + c];
        s += __shfl_xor(s, 1);
        s += __shfl_xor(s, 2);
        s += __shfl_xor(s, 4);
        s += __shfl_xor(s, 8);
        if (r == 0) tot[c] = s;
    }
    __syncthreads();
    if (threadIdx.x < C) {
        const int cc = threadIdx.x;
        const float invN = 1.0f / (float)N_ROWS;
        float mean = tot[cc] * invN;
        float var = tot[C + cc] * invN - mean * mean;
        float scale = g[cc] * rsqrtf(var + EPS);
        ss[cc] = scale;
        ss[C + cc] = be[cc] - mean * scale;
    }
}

// ---------- kB: x = bn1(feature@W1+b1) materialized as fp16 rows ----------

template <int RPU>
__global__ __launch_bounds__(BLK, 4) void kB(const float* __restrict__ feat,
                                             const float* __restrict__ W1,
                                             const float* __restrict__ b1,
                                             const float* __restrict__ ss1,
                                             unsigned int* __restrict__ xh) {
    const int n = blockIdx.x * BLK + threadIdx.x;
    if (n >= N_ROWS) return;
    float f[C];
    load_row20_nt(feat + (size_t)n * C, f);
    float y[C];
#pragma unroll
    for (int c = 0; c < C; c++) y[c] = b1[c];
#pragma unroll
    for (int i = 0; i < C; i++) {
        float fi = f[i];
#pragma unroll
        for (int c = 0; c < C; c++) y[c] = fmaf(fi, W1[i * C + c], y[c]);
    }
    float x[C];
#pragma unroll
    for (int c = 0; c < C; c++) x[c] = fmaf(y[c], ss1[c], ss1[C + c]);
    store_row_h<RPU>(xh + (size_t)n * RPU, x);
}

// ---------- kC: attention pass 1 (online softmax) ----------

template <int RPU>
__global__ __launch_bounds__(BLK, 4) void kC(const unsigned int* __restrict__ xh,
                                             const int* __restrict__ index,
                                             float* __restrict__ wbuf,
                                             unsigned int* __restrict__ oh) {
    const int n = blockIdx.x * BLK + threadIdx.x;
    if (n >= N_ROWS) return;

    float x[C];
    load_row_h<RPU>(xh + (size_t)n * RPU, x);

    int idx[K];
#pragma unroll
    for (int k = 0; k < K; k++) idx[k] = ntl(index + (size_t)n * K + k);

    float m = -INFINITY, l = 0.f;
    float acc[C];
    float s[K];
#pragma unroll
    for (int c = 0; c < C; c++) acc[c] = 0.f;

#pragma unroll
    for (int k = 0; k < K; k++) {
        float gch[C];
        load_row_h<RPU>(xh + (size_t)idx[k] * RPU, gch);
        float d0 = 0.f, d1 = 0.f;
#pragma unroll
        for (int c = 0; c < C; c += 2) {
            d0 = fmaf(x[c], gch[c], d0);
            d1 = fmaf(x[c + 1], gch[c + 1], d1);
        }
        const float dot = d0 + d1;
        s[k] = dot;
        const float mn = fmaxf(m, dot);
        const float rr = __expf(m - mn);
        const float pp = __expf(dot - mn);
        l = fmaf(l, rr, pp);
#pragma unroll
        for (int c = 0; c < C; c++) acc[c] = fmaf(acc[c], rr, pp * gch[c]);
        m = mn;
    }

    const float linv = 1.f / l;
    float o[C];
#pragma unroll
    for (int c = 0; c < C; c++) o[c] = acc[c] * linv;
    store_row_h<RPU>(oh + (size_t)n * RPU, o);
#pragma unroll
    for (int k = 0; k < K; k++) nts(wbuf + (size_t)k * N_ROWS + n, __expf(s[k] - m) * linv);
}

// ---------- kD: pass 2 aggregation with same weights + BN2 stats ----------

template <int RPU>
__global__ __launch_bounds__(BLK, 3) void kD(const unsigned int* __restrict__ oh,
                                             const int* __restrict__ index,
                                             const float* __restrict__ wbuf,
                                             float* __restrict__ out2,
                                             float* __restrict__ partials) {
    float sums[2 * C];
#pragma unroll
    for (int i = 0; i < 2 * C; i++) sums[i] = 0.f;

    for (int n = blockIdx.x * BLK + threadIdx.x; n < N_ROWS; n += GRID_RED * BLK) {
        float wv[K];
        int idx[K];
#pragma unroll
        for (int k = 0; k < K; k++) {
            wv[k] = ntl(wbuf + (size_t)k * N_ROWS + n);
            idx[k] = ntl(index + (size_t)n * K + k);
        }
        float acc[C];
#pragma unroll
        for (int c = 0; c < C; c++) acc[c] = 0.f;
#pragma unroll
        for (int k = 0; k < K; k++) {
            float t[C];
            load_row_h<RPU>(oh + (size_t)idx[k] * RPU, t);
#pragma unroll
            for (int c = 0; c < C; c++) acc[c] = fmaf(wv[k], t[c], acc[c]);
        }
        store_row20_nt(out2 + (size_t)n * C, acc);
#pragma unroll
        for (int c = 0; c < C; c++) {
            sums[c] += acc[c];
            sums[C + c] = fmaf(acc[c], acc[c], sums[C + c]);
        }
    }
    block_reduce_partials(sums, partials);
}

// ---------- kF: z = [relu(bn2(out2)), feature] @ W3 + b3 (in place) + BN3 stats ----------

__global__ __launch_bounds__(BLK, 3) void kF(const float* __restrict__ feat,
                                             const float* __restrict__ W3,
                                             const float* __restrict__ b3,
                                             const float* __restrict__ ss2,
                                             float* __restrict__ zio,
                                             float* __restrict__ partials) {
    float sums[2 * C];
#pragma unroll
    for (int i = 0; i < 2 * C; i++) sums[i] = 0.f;

    for (int n = blockIdx.x * BLK + threadIdx.x; n < N_ROWS; n += GRID_RED * BLK) {
        float h[2 * C];
        {
            float t[C];
            load_row20_nt(zio + (size_t)n * C, t);
#pragma unroll
            for (int c = 0; c < C; c++) h[c] = fmaxf(0.f, fmaf(t[c], ss2[c], ss2[C + c]));
        }
        load_row20_nt(feat + (size_t)n * C, h + C);

        float z[C];
#pragma unroll
        for (int c = 0; c < C; c++) z[c] = b3[c];
#pragma unroll
        for (int i = 0; i < 2 * C; i++) {
            float hi = h[i];
#pragma unroll
            for (int c = 0; c < C; c++) z[c] = fmaf(hi, W3[i * C + c], z[c]);
        }
        store_row20_nt(zio + (size_t)n * C, z);
#pragma unroll
        for (int c = 0; c < C; c++) {
            sums[c] += z[c];
            sums[C + c] = fmaf(z[c], z[c], sums[C + c]);
        }
    }
    block_reduce_partials(sums, partials);
}

// ---------- kH: final bn3 + relu (in place) ----------

__global__ __launch_bounds__(BLK, 4) void kH(float* __restrict__ zio,
                                             const float* __restrict__ ss3) {
    for (int n = blockIdx.x * BLK + threadIdx.x; n < N_ROWS; n += GRID_RED * BLK) {
        float t[C];
        load_row20_nt(zio + (size_t)n * C, t);
        float o[C];
#pragma unroll
        for (int c = 0; c < C; c++) o[c] = fmaxf(0.f, fmaf(t[c], ss3[c], ss3[C + c]));
        store_row20_nt(zio + (size_t)n * C, o);
    }
}

// ---------- launch ----------

template <int RPU>
static void launch_all(const float* feature, const int* index, const float* W1,
                       const float* b1, const float* g1, const float* be1,
                       const float* g2, const float* be2, const float* W3,
                       const float* b3, const float* g3, const float* be3,
                       float* outp, void* d_ws, hipStream_t stream) {
    unsigned int* xh = (unsigned int*)d_ws;
    unsigned int* oh = xh + (size_t)N_ROWS * RPU;
    float* wbuf = (float*)(oh + (size_t)N_ROWS * RPU);
    float* partials = wbuf + (size_t)N_ROWS * K;
    float* ss1 = partials + (size_t)GRID_RED * (2 * C);
    float* ss2 = ss1 + 2 * C;
    float* ss3 = ss2 + 2 * C;

    const int gridR = (N_ROWS + BLK - 1) / BLK;

    kA<<<GRID_RED, BLK, 0, stream>>>(feature, W1, b1, partials);
    kFin<<<1, 640, 0, stream>>>(partials, g1, be1, ss1);
    kB<RPU><<<gridR, BLK, 0, stream>>>(feature, W1, b1, ss1, xh);
    kC<RPU><<<gridR, BLK, 0, stream>>>(xh, index, wbuf, oh);
    kD<RPU><<<GRID_RED, BLK, 0, stream>>>(oh, index, wbuf, outp, partials);
    kFin<<<1, 640, 0, stream>>>(partials, g2, be2, ss2);
    kF<<<GRID_RED, BLK, 0, stream>>>(feature, W3, b3, ss2, outp, partials);
    kFin<<<1, 640, 0, stream>>>(partials, g3, be3, ss3);
    kH<<<GRID_RED, BLK, 0, stream>>>(outp, ss3);
}

extern "C" void kernel_launch(void* const* d_in, const int* in_sizes, int n_in,
                              void* d_out, int out_size, void* d_ws, size_t ws_size,
                              hipStream_t stream) {
    const float* feature = (const float*)d_in[0];
    const int* index = (const int*)d_in[1];
    const float* W1 = (const float*)d_in[2];
    const float* b1 = (const float*)d_in[3];
    const float* g1 = (const float*)d_in[4];
    const float* be1 = (const float*)d_in[5];
    const float* g2 = (const float*)d_in[6];
    const float* be2 = (const float*)d_in[7];
    const float* W3 = (const float*)d_in[8];
    const float* b3 = (const float*)d_in[9];
    const float* g3 = (const float*)d_in[10];
    const float* be3 = (const float*)d_in[11];
    float* outp = (float*)d_out;

    // padded layout (64B fp16 rows): 2 * N*16*4 + wbuf + partials + ss
    const size_t need32 = (size_t)N_ROWS * 16 * 4 * 2 + (size_t)N_ROWS * K * 4 +
                          (size_t)GRID_RED * (2 * C) * 4 + 6 * C * 4 + 1024;

    if (ws_size >= need32) {
        launch_all<16>(feature, index, W1, b1, g1, be1, g2, be2, W3, b3, g3, be3,
                       outp, d_ws, stream);
    } else {
        launch_all<10>(feature, index, W1, b1, g1, be1, g2, be2, W3, b3, g3, be3,
                       outp, d_ws, stream);
    }
}